// Round 3
// baseline (271.667 us; speedup 1.0000x reference)
//
#include <hip/hip_runtime.h>
#include <math.h>

// ---------------------------------------------------------------------------
// AttentionLayer: out = softmax(mask(q k^T * scale)) @ v,  q/k/v = x@W + b
// B=4, T=2048, C=H=768.  bf16 MFMA (16x16x32), fp32 accumulate.
// R2: revert R1 dbuf (regressed: VALUBusy 11->31, qkv 66->83us).
//     S stored fp16; softmax replaced by rowstat (M, 1/L only); o_gemm fuses
//     the softmax apply into its A-tile staging (P never materialized).
// ---------------------------------------------------------------------------

#define BB 4
#define TT 2048
#define CC 768

typedef __bf16 bf16_t;
typedef __bf16 bf16x8 __attribute__((ext_vector_type(8)));
typedef _Float16 half8 __attribute__((ext_vector_type(8)));
typedef float f32x4 __attribute__((ext_vector_type(4)));

// ---------------------------------------------------------------------------
// async global->LDS 16B copy (wave-uniform LDS base + lane*16 implicit)
// ---------------------------------------------------------------------------
__device__ __forceinline__ void async_load16(void* lds, const void* g) {
  __builtin_amdgcn_global_load_lds(
      (const __attribute__((address_space(1))) void*)g,
      (__attribute__((address_space(3))) void*)lds, 16, 0, 0);
}

// Stage a 128x32 bf16 tile (row-major, row stride ld elements) into LDS.
// LDS layout: row-major 128x32, 8-elem chunks XOR-swizzled within a row:
// physical chunk p of row r holds logical chunk q = p ^ (r & 3).
__device__ __forceinline__ void stage_tile(const bf16_t* __restrict__ g0,
                                           int ld, bf16_t* lds, int t) {
  int w = t >> 6, l = t & 63;
#pragma unroll
  for (int i = 0; i < 2; ++i) {
    int c = i * 256 + w * 64 + l;   // linear 16B-chunk id in LDS
    int row = c >> 2;
    int p = c & 3;
    int q = p ^ (row & 3);          // logical chunk to fetch
    async_load16(lds + i * 2048 + w * 512,  // wave-uniform base (elements)
                 g0 + row * ld + q * 8);
  }
}

// Read one MFMA fragment (8 bf16, 16B) for logical (row r, k-chunk q).
__device__ __forceinline__ bf16x8 read_frag(const bf16_t* lds, int r, int q) {
  int p = q ^ (r & 3);
  return *(const bf16x8*)(lds + r * 32 + p * 8);
}

// Core: C[128x128] += A[128xK] * B^T, single-buffered (R0 known-good).
__device__ __forceinline__ void gemm_core(const bf16_t* __restrict__ A, int lda,
                                          const bf16_t* __restrict__ B, int ldb,
                                          int kTiles, bf16_t* As, bf16_t* Bs,
                                          f32x4 acc[4][4]) {
  int t = threadIdx.x;
  int l = t & 63;
  int w = t >> 6;
  int wr = (w >> 1) * 64;  // wave row offset in 128-tile
  int wc = (w & 1) * 64;   // wave col offset

  for (int kt = 0; kt < kTiles; ++kt) {
    __syncthreads();  // previous iteration's LDS reads done
    stage_tile(A + kt * 32, lda, As, t);
    stage_tile(B + kt * 32, ldb, Bs, t);
    __syncthreads();  // staging complete

    bf16x8 af[4], bfr[4];
    int q = l >> 4;
#pragma unroll
    for (int i = 0; i < 4; ++i) {
      af[i] = read_frag(As, wr + i * 16 + (l & 15), q);
      bfr[i] = read_frag(Bs, wc + i * 16 + (l & 15), q);
    }
#pragma unroll
    for (int mi = 0; mi < 4; ++mi)
#pragma unroll
      for (int ni = 0; ni < 4; ++ni)
        acc[mi][ni] = __builtin_amdgcn_mfma_f32_16x16x32_bf16(
            af[mi], bfr[ni], acc[mi][ni], 0, 0, 0);
  }
}

// C/D layout (m89-verified): col = lane&15, row = (lane>>4)*4 + reg.

// ---------------------------------------------------------------------------
// Kernel 1: cast x (fp32) -> bf16, 8 elems/thread
// ---------------------------------------------------------------------------
__global__ __launch_bounds__(256) void cast_x_kernel(
    const float* __restrict__ x, bf16_t* __restrict__ xbf) {
  int i = blockIdx.x * 256 + threadIdx.x;
  const float4* xin = (const float4*)x;
  float4 a = xin[i * 2];
  float4 b = xin[i * 2 + 1];
  bf16_t tmp[8];
  tmp[0] = (bf16_t)a.x; tmp[1] = (bf16_t)a.y;
  tmp[2] = (bf16_t)a.z; tmp[3] = (bf16_t)a.w;
  tmp[4] = (bf16_t)b.x; tmp[5] = (bf16_t)b.y;
  tmp[6] = (bf16_t)b.z; tmp[7] = (bf16_t)b.w;
  *(uint4*)(xbf + (size_t)i * 8) = *(const uint4*)tmp;
}

// ---------------------------------------------------------------------------
// Kernel 2: transpose+cast the three weight matrices [C][H] -> bf16 [H][C]
// ---------------------------------------------------------------------------
__global__ __launch_bounds__(256) void transpose_w_kernel(
    const float* __restrict__ Wq, const float* __restrict__ Wk,
    const float* __restrict__ Wv, bf16_t* __restrict__ wt) {
  int z = blockIdx.z;
  const float* W = (z == 0) ? Wq : (z == 1) ? Wk : Wv;
  bf16_t* out = wt + (size_t)z * CC * CC;
  __shared__ float tile[32][33];
  int tx = threadIdx.x;  // 0..31
  int ty = threadIdx.y;  // 0..7
  int n0 = blockIdx.x * 32;
  int c0 = blockIdx.y * 32;
#pragma unroll
  for (int k = 0; k < 4; ++k)
    tile[ty + k * 8][tx] = W[(size_t)(c0 + ty + k * 8) * CC + n0 + tx];
  __syncthreads();
#pragma unroll
  for (int k = 0; k < 4; ++k)
    out[(size_t)(n0 + ty + k * 8) * CC + c0 + tx] =
        (bf16_t)tile[tx][ty + k * 8];
}

// ---------------------------------------------------------------------------
// Kernel 3: QKV GEMM.  z=0: q (scaled by H^-1/2), z=1: k, z=2: v transposed.
// ---------------------------------------------------------------------------
__global__ __launch_bounds__(256) void qkv_gemm_kernel(
    const bf16_t* __restrict__ xbf, const bf16_t* __restrict__ wt,
    const float* __restrict__ bq, const float* __restrict__ bk,
    const float* __restrict__ bv, bf16_t* __restrict__ qb,
    bf16_t* __restrict__ kb, bf16_t* __restrict__ vt) {
  __shared__ bf16_t As[128 * 32];
  __shared__ bf16_t Bs[128 * 32];
  int n0 = blockIdx.x * 128;
  int m0 = blockIdx.y * 128;
  int z = blockIdx.z;

  f32x4 acc[4][4];
#pragma unroll
  for (int i = 0; i < 4; ++i)
#pragma unroll
    for (int j = 0; j < 4; ++j) acc[i][j] = (f32x4){0.f, 0.f, 0.f, 0.f};

  const bf16_t* A = xbf + (size_t)m0 * CC;
  const bf16_t* B = wt + (size_t)z * CC * CC + (size_t)n0 * CC;
  gemm_core(A, CC, B, CC, CC / 32, As, Bs, acc);

  int l = threadIdx.x & 63, w = threadIdx.x >> 6;
  int wr = (w >> 1) * 64, wc = (w & 1) * 64;
  const float* bias = (z == 0) ? bq : (z == 1) ? bk : bv;
  float scale = (z == 0) ? rsqrtf((float)CC) : 1.0f;

#pragma unroll
  for (int mi = 0; mi < 4; ++mi) {
#pragma unroll
    for (int ni = 0; ni < 4; ++ni) {
      int col = n0 + wc + ni * 16 + (l & 15);
      int rbase = m0 + wr + mi * 16 + (l >> 4) * 4;
      float bcol = bias[col];
#pragma unroll
      for (int r = 0; r < 4; ++r) {
        int m = rbase + r;
        float v = (acc[mi][ni][r] + bcol) * scale;
        bf16_t h = (bf16_t)v;
        if (z == 0) {
          qb[(size_t)m * CC + col] = h;
        } else if (z == 1) {
          kb[(size_t)m * CC + col] = h;
        } else {
          int b = m >> 11, tt = m & (TT - 1);
          vt[((size_t)b * CC + col) * TT + tt] = h;  // v^T: [B][H][T]
        }
      }
    }
  }
}

// ---------------------------------------------------------------------------
// Kernel 4: S = q k^T (scale folded into q), causal mask + (==0 -> -inf),
// stored as fp16 (10-bit mantissa keeps exp(s-M) error < 0.1%).
// Only lower-triangular 128x128 blocks computed.
// ---------------------------------------------------------------------------
__global__ __launch_bounds__(256) void s_gemm_kernel(
    const bf16_t* __restrict__ qb, const bf16_t* __restrict__ kb,
    _Float16* __restrict__ S) {
  int tj = blockIdx.x, ti = blockIdx.y, b = blockIdx.z;
  if (tj > ti) return;
  __shared__ bf16_t As[128 * 32];
  __shared__ bf16_t Bs[128 * 32];
  int m0 = ti * 128, n0 = tj * 128;

  f32x4 acc[4][4];
#pragma unroll
  for (int i = 0; i < 4; ++i)
#pragma unroll
    for (int j = 0; j < 4; ++j) acc[i][j] = (f32x4){0.f, 0.f, 0.f, 0.f};

  const bf16_t* A = qb + ((size_t)b * TT + m0) * CC;
  const bf16_t* B = kb + ((size_t)b * TT + n0) * CC;
  gemm_core(A, CC, B, CC, CC / 32, As, Bs, acc);

  _Float16* Sb = S + (size_t)b * TT * TT;
  int l = threadIdx.x & 63, w = threadIdx.x >> 6;
  int wr = (w >> 1) * 64, wc = (w & 1) * 64;
#pragma unroll
  for (int mi = 0; mi < 4; ++mi) {
#pragma unroll
    for (int ni = 0; ni < 4; ++ni) {
      int j = n0 + wc + ni * 16 + (l & 15);
      int ibase = m0 + wr + mi * 16 + (l >> 4) * 4;
#pragma unroll
      for (int r = 0; r < 4; ++r) {
        int i = ibase + r;
        float v = acc[mi][ni][r];
        if (j > i || v == 0.0f) v = -INFINITY;  // causal + reference quirk
        Sb[(size_t)i * TT + j] = (_Float16)v;
      }
    }
  }
}

// ---------------------------------------------------------------------------
// Kernel 5: rowstat — per-row max M and 1/sum(exp(s-M)).  One half8 load per
// thread covers the whole causal row (pe <= 2048 = 256 threads * 8).
// Cols in [len, pe) hold -inf from the diagonal tile -> contribute 0.
// ---------------------------------------------------------------------------
__global__ __launch_bounds__(256) void rowstat_kernel(
    const _Float16* __restrict__ S, float* __restrict__ Mrow,
    float* __restrict__ Linv) {
  int row = blockIdx.x & (TT - 1);
  int b = blockIdx.x >> 11;
  const _Float16* s = S + ((size_t)b * TT + row) * TT;
  int pe = ((row >> 7) + 1) << 7;  // padded causal length, multiple of 128
  int j = threadIdx.x * 8;

  float f[8];
  if (j < pe) {
    half8 h = *(const half8*)(s + j);
#pragma unroll
    for (int k = 0; k < 8; ++k) f[k] = (float)h[k];
  } else {
#pragma unroll
    for (int k = 0; k < 8; ++k) f[k] = -INFINITY;
  }

  float m = f[0];
#pragma unroll
  for (int k = 1; k < 8; ++k) m = fmaxf(m, f[k]);
#pragma unroll
  for (int off = 32; off > 0; off >>= 1) m = fmaxf(m, __shfl_xor(m, off));
  __shared__ float redm[4];
  int w = threadIdx.x >> 6, l = threadIdx.x & 63;
  if (l == 0) redm[w] = m;
  __syncthreads();
  m = fmaxf(fmaxf(redm[0], redm[1]), fmaxf(redm[2], redm[3]));

  float sum = 0.f;
#pragma unroll
  for (int k = 0; k < 8; ++k) sum += __expf(f[k] - m);  // exp(-inf)=0
#pragma unroll
  for (int off = 32; off > 0; off >>= 1) sum += __shfl_xor(sum, off);
  __shared__ float reds[4];
  if (l == 0) reds[w] = sum;
  __syncthreads();
  if (threadIdx.x == 0) {
    float L = reds[0] + reds[1] + reds[2] + reds[3];
    Mrow[blockIdx.x] = m;
    Linv[blockIdx.x] = 1.0f / L;
  }
}

// ---------------------------------------------------------------------------
// Kernel 6: O = P @ V with P computed on the fly from fp16 S:
//   p = exp(s - M[row]) * Linv[row], cast bf16, written into the XOR-swizzled
//   LDS A-tile via paired 16B ds_writes.  B = v^T staged async as before.
// K-loop truncated at the causal boundary: kt < (ti+1)*4.
// ---------------------------------------------------------------------------
__global__ __launch_bounds__(256) void o_gemm_kernel(
    const _Float16* __restrict__ S, const bf16_t* __restrict__ vt,
    const float* __restrict__ Mrow, const float* __restrict__ Linv,
    float* __restrict__ out) {
  int nj = blockIdx.x, ti = blockIdx.y, b = blockIdx.z;
  __shared__ bf16_t As[128 * 32];
  __shared__ bf16_t Bs[128 * 32];
  int m0 = ti * 128, n0 = nj * 128;
  int t = threadIdx.x, l = t & 63, w = t >> 6;
  int wr = (w >> 1) * 64, wc = (w & 1) * 64;

  // A-staging assignment: thread t owns row arow = t>>1, physical chunk pair
  // {P0, P0+1} with P0 = (t&1)*2.  Logical chunks covered = {qbase, qbase+1},
  // qbase = P0 ^ (arow&2); physical slot of logical qbase = P0 ^ (arow&1).
  int arow = t >> 1;
  int P0 = (t & 1) * 2;
  int qbase = P0 ^ (arow & 2);
  const _Float16* ag =
      S + ((size_t)b * TT + m0 + arow) * TT + qbase * 8;
  float M = Mrow[b * TT + m0 + arow];
  float Li = Linv[b * TT + m0 + arow];
  bf16x8* dst = (bf16x8*)(As + arow * 32 + P0 * 8);
  int swap = arow & 1;

  const bf16_t* Bt = vt + ((size_t)b * CC + n0) * TT;
  int kTiles = (ti + 1) * 4;

  f32x4 acc[4][4];
#pragma unroll
  for (int i = 0; i < 4; ++i)
#pragma unroll
    for (int j = 0; j < 4; ++j) acc[i][j] = (f32x4){0.f, 0.f, 0.f, 0.f};

  for (int kt = 0; kt < kTiles; ++kt) {
    __syncthreads();  // previous iteration's LDS reads done
    stage_tile(Bt + kt * 32, TT, Bs, t);  // async B
    // A: VGPR round-trip with fused softmax apply
    half8 ha = *(const half8*)(ag + kt * 32);
    half8 hb = *(const half8*)(ag + kt * 32 + 8);
    bf16x8 ca, cb;
#pragma unroll
    for (int k2 = 0; k2 < 8; ++k2) {
      ca[k2] = (bf16_t)(__expf((float)ha[k2] - M) * Li);
      cb[k2] = (bf16_t)(__expf((float)hb[k2] - M) * Li);
    }
    if (swap) { dst[0] = cb; dst[1] = ca; }
    else      { dst[0] = ca; dst[1] = cb; }
    __syncthreads();  // staging complete (lgkm + vm drained)

    bf16x8 af[4], bfr[4];
    int q = l >> 4;
#pragma unroll
    for (int i = 0; i < 4; ++i) {
      af[i] = read_frag(As, wr + i * 16 + (l & 15), q);
      bfr[i] = read_frag(Bs, wc + i * 16 + (l & 15), q);
    }
#pragma unroll
    for (int mi = 0; mi < 4; ++mi)
#pragma unroll
      for (int ni = 0; ni < 4; ++ni)
        acc[mi][ni] = __builtin_amdgcn_mfma_f32_16x16x32_bf16(
            af[mi], bfr[ni], acc[mi][ni], 0, 0, 0);
  }

  float* Ob = out + (size_t)b * TT * CC;
#pragma unroll
  for (int mi = 0; mi < 4; ++mi) {
#pragma unroll
    for (int ni = 0; ni < 4; ++ni) {
      int col = n0 + wc + ni * 16 + (l & 15);
      int ibase = m0 + wr + mi * 16 + (l >> 4) * 4;
#pragma unroll
      for (int r = 0; r < 4; ++r)
        Ob[(size_t)(ibase + r) * CC + col] = acc[mi][ni][r];
    }
  }
}

// ---------------------------------------------------------------------------
extern "C" void kernel_launch(void* const* d_in, const int* in_sizes, int n_in,
                              void* d_out, int out_size, void* d_ws,
                              size_t ws_size, hipStream_t stream) {
  const float* x = (const float*)d_in[0];
  const float* Wq = (const float*)d_in[1];
  const float* bq = (const float*)d_in[2];
  const float* Wk = (const float*)d_in[3];
  const float* bk = (const float*)d_in[4];
  const float* Wv = (const float*)d_in[5];
  const float* bv = (const float*)d_in[6];
  float* out = (float*)d_out;

  char* ws = (char*)d_ws;
  size_t off = 0;
  auto carve = [&](size_t bytes) -> char* {
    char* p = ws + off;
    off += (bytes + 255) & ~(size_t)255;
    return p;
  };
  const size_t M = (size_t)BB * TT;  // 8192
  bf16_t* xbf = (bf16_t*)carve(M * CC * 2);            // 12.6 MB
  bf16_t* wt  = (bf16_t*)carve(3ull * CC * CC * 2);    // 3.5 MB
  bf16_t* qb  = (bf16_t*)carve(M * CC * 2);            // 12.6 MB
  bf16_t* kb  = (bf16_t*)carve(M * CC * 2);            // 12.6 MB
  bf16_t* vt  = (bf16_t*)carve(M * CC * 2);            // 12.6 MB (as [B][H][T])
  _Float16* S = (_Float16*)carve((size_t)BB * TT * TT * 2);  // 33.5 MB
  float* Mrow = (float*)carve(M * 4);                  // 32 KB
  float* Linv = (float*)carve(M * 4);                  // 32 KB
  (void)off; (void)ws_size;

  // 1+2: input prep
  cast_x_kernel<<<(M * CC / 8 + 255) / 256, 256, 0, stream>>>(x, xbf);
  transpose_w_kernel<<<dim3(CC / 32, CC / 32, 3), dim3(32, 8, 1), 0, stream>>>(
      Wq, Wk, Wv, wt);
  // 3: q,k,v
  qkv_gemm_kernel<<<dim3(CC / 128, M / 128, 3), 256, 0, stream>>>(
      xbf, wt, bq, bk, bv, qb, kb, vt);
  // 4: S = q k^T (lower-tri blocks, fp16)
  s_gemm_kernel<<<dim3(TT / 128, TT / 128, BB), 256, 0, stream>>>(qb, kb, S);
  // 5: per-row M, 1/L
  rowstat_kernel<<<BB * TT, 256, 0, stream>>>(S, Mrow, Linv);
  // 6: O = softmax(S) V, softmax applied during A-staging
  o_gemm_kernel<<<dim3(CC / 128, TT / 128, BB), 256, 0, stream>>>(
      S, vt, Mrow, Linv, out);
}

// Round 4
// 236.724 us; speedup vs baseline: 1.1476x; 1.1476x over previous
//
#include <hip/hip_runtime.h>
#include <math.h>

// ---------------------------------------------------------------------------
// AttentionLayer: out = softmax(mask(q k^T * scale)) @ v,  q/k/v = x@W + b
// B=4, T=2048, C=H=768.  bf16 MFMA (16x16x32), fp32 accumulate.
// R3: gemm_core = unroll-2 STATIC double-buffer (1 barrier/k-tile; R1's
//     dynamic-toggle version regressed via VALU blowup, this one has
//     compile-time buffer addresses).  rowstat now also writes normalized
//     P (bf16) since it already holds exp(s-M) in registers; o_gemm back to
//     the R0 fully-async no-exp structure, heavy tiles first.
// ---------------------------------------------------------------------------

#define BB 4
#define TT 2048
#define CC 768

typedef __bf16 bf16_t;
typedef __bf16 bf16x8 __attribute__((ext_vector_type(8)));
typedef _Float16 half8 __attribute__((ext_vector_type(8)));
typedef float f32x4 __attribute__((ext_vector_type(4)));

// ---------------------------------------------------------------------------
// async global->LDS 16B copy (wave-uniform LDS base + lane*16 implicit)
// ---------------------------------------------------------------------------
__device__ __forceinline__ void async_load16(void* lds, const void* g) {
  __builtin_amdgcn_global_load_lds(
      (const __attribute__((address_space(1))) void*)g,
      (__attribute__((address_space(3))) void*)lds, 16, 0, 0);
}

// Stage a 128x32 bf16 tile (row-major, row stride ld elements) into LDS.
// LDS layout: row-major 128x32, 8-elem chunks XOR-swizzled within a row:
// physical chunk p of row r holds logical chunk q = p ^ (r & 3).
__device__ __forceinline__ void stage_tile(const bf16_t* __restrict__ g0,
                                           int ld, bf16_t* lds, int t) {
  int w = t >> 6, l = t & 63;
#pragma unroll
  for (int i = 0; i < 2; ++i) {
    int c = i * 256 + w * 64 + l;   // linear 16B-chunk id in LDS
    int row = c >> 2;
    int p = c & 3;
    int q = p ^ (row & 3);          // logical chunk to fetch
    async_load16(lds + i * 2048 + w * 512,  // wave-uniform base (elements)
                 g0 + row * ld + q * 8);
  }
}

// Read one MFMA fragment (8 bf16, 16B) for logical (row r, k-chunk q).
__device__ __forceinline__ bf16x8 read_frag(const bf16_t* lds, int r, int q) {
  int p = q ^ (r & 3);
  return *(const bf16x8*)(lds + r * 32 + p * 8);
}

// One 128x128x32 MFMA step from a published LDS buffer pair.
__device__ __forceinline__ void mfma_tile(const bf16_t* Ab, const bf16_t* Bb,
                                          int wr, int wc, int l,
                                          f32x4 acc[4][4]) {
  bf16x8 af[4], bfr[4];
  int q = l >> 4;
#pragma unroll
  for (int i = 0; i < 4; ++i) {
    af[i] = read_frag(Ab, wr + i * 16 + (l & 15), q);
    bfr[i] = read_frag(Bb, wc + i * 16 + (l & 15), q);
  }
#pragma unroll
  for (int mi = 0; mi < 4; ++mi)
#pragma unroll
    for (int ni = 0; ni < 4; ++ni)
      acc[mi][ni] = __builtin_amdgcn_mfma_f32_16x16x32_bf16(
          af[mi], bfr[ni], acc[mi][ni], 0, 0, 0);
}

// Core: C[128x128] += A[128xK] * B^T.  kTiles must be EVEN.
// Unroll-2 static double-buffer: one barrier per k-tile; each async stage has
// a full MFMA phase in flight before the barrier that drains it.
__device__ __forceinline__ void gemm_core(const bf16_t* __restrict__ A, int lda,
                                          const bf16_t* __restrict__ B, int ldb,
                                          int kTiles, bf16_t* As0, bf16_t* As1,
                                          bf16_t* Bs0, bf16_t* Bs1,
                                          f32x4 acc[4][4]) {
  int t = threadIdx.x;
  int l = t & 63;
  int w = t >> 6;
  int wr = (w >> 1) * 64;  // wave row offset in 128-tile
  int wc = (w & 1) * 64;   // wave col offset

  stage_tile(A, lda, As0, t);  // k-tile 0 -> buf0
  stage_tile(B, ldb, Bs0, t);

  for (int kt = 0; kt < kTiles; kt += 2) {
    __syncthreads();  // publish buf0(kt); prior buf1 reads complete
    stage_tile(A + (kt + 1) * 32, lda, As1, t);   // prefetch kt+1
    stage_tile(B + (kt + 1) * 32, ldb, Bs1, t);
    mfma_tile(As0, Bs0, wr, wc, l, acc);
    __syncthreads();  // publish buf1(kt+1); buf0 reads complete
    if (kt + 2 < kTiles) {
      stage_tile(A + (kt + 2) * 32, lda, As0, t);  // prefetch kt+2
      stage_tile(B + (kt + 2) * 32, ldb, Bs0, t);
    }
    mfma_tile(As1, Bs1, wr, wc, l, acc);
  }
}

// C/D layout (m89-verified): col = lane&15, row = (lane>>4)*4 + reg.

// ---------------------------------------------------------------------------
// Kernel 1: cast x (fp32) -> bf16, 8 elems/thread
// ---------------------------------------------------------------------------
__global__ __launch_bounds__(256) void cast_x_kernel(
    const float* __restrict__ x, bf16_t* __restrict__ xbf) {
  int i = blockIdx.x * 256 + threadIdx.x;
  const float4* xin = (const float4*)x;
  float4 a = xin[i * 2];
  float4 b = xin[i * 2 + 1];
  bf16_t tmp[8];
  tmp[0] = (bf16_t)a.x; tmp[1] = (bf16_t)a.y;
  tmp[2] = (bf16_t)a.z; tmp[3] = (bf16_t)a.w;
  tmp[4] = (bf16_t)b.x; tmp[5] = (bf16_t)b.y;
  tmp[6] = (bf16_t)b.z; tmp[7] = (bf16_t)b.w;
  *(uint4*)(xbf + (size_t)i * 8) = *(const uint4*)tmp;
}

// ---------------------------------------------------------------------------
// Kernel 2: transpose+cast the three weight matrices [C][H] -> bf16 [H][C]
// ---------------------------------------------------------------------------
__global__ __launch_bounds__(256) void transpose_w_kernel(
    const float* __restrict__ Wq, const float* __restrict__ Wk,
    const float* __restrict__ Wv, bf16_t* __restrict__ wt) {
  int z = blockIdx.z;
  const float* W = (z == 0) ? Wq : (z == 1) ? Wk : Wv;
  bf16_t* out = wt + (size_t)z * CC * CC;
  __shared__ float tile[32][33];
  int tx = threadIdx.x;  // 0..31
  int ty = threadIdx.y;  // 0..7
  int n0 = blockIdx.x * 32;
  int c0 = blockIdx.y * 32;
#pragma unroll
  for (int k = 0; k < 4; ++k)
    tile[ty + k * 8][tx] = W[(size_t)(c0 + ty + k * 8) * CC + n0 + tx];
  __syncthreads();
#pragma unroll
  for (int k = 0; k < 4; ++k)
    out[(size_t)(n0 + ty + k * 8) * CC + c0 + tx] =
        (bf16_t)tile[tx][ty + k * 8];
}

// ---------------------------------------------------------------------------
// Kernel 3: QKV GEMM.  z=0: q (scaled by H^-1/2), z=1: k, z=2: v transposed.
// ---------------------------------------------------------------------------
__global__ __launch_bounds__(256) void qkv_gemm_kernel(
    const bf16_t* __restrict__ xbf, const bf16_t* __restrict__ wt,
    const float* __restrict__ bq, const float* __restrict__ bk,
    const float* __restrict__ bv, bf16_t* __restrict__ qb,
    bf16_t* __restrict__ kb, bf16_t* __restrict__ vt) {
  __shared__ bf16_t As0[4096], As1[4096], Bs0[4096], Bs1[4096];
  int n0 = blockIdx.x * 128;
  int m0 = blockIdx.y * 128;
  int z = blockIdx.z;

  f32x4 acc[4][4];
#pragma unroll
  for (int i = 0; i < 4; ++i)
#pragma unroll
    for (int j = 0; j < 4; ++j) acc[i][j] = (f32x4){0.f, 0.f, 0.f, 0.f};

  const bf16_t* A = xbf + (size_t)m0 * CC;
  const bf16_t* B = wt + (size_t)z * CC * CC + (size_t)n0 * CC;
  gemm_core(A, CC, B, CC, CC / 32, As0, As1, Bs0, Bs1, acc);

  int l = threadIdx.x & 63, w = threadIdx.x >> 6;
  int wr = (w >> 1) * 64, wc = (w & 1) * 64;
  const float* bias = (z == 0) ? bq : (z == 1) ? bk : bv;
  float scale = (z == 0) ? rsqrtf((float)CC) : 1.0f;

#pragma unroll
  for (int mi = 0; mi < 4; ++mi) {
#pragma unroll
    for (int ni = 0; ni < 4; ++ni) {
      int col = n0 + wc + ni * 16 + (l & 15);
      int rbase = m0 + wr + mi * 16 + (l >> 4) * 4;
      float bcol = bias[col];
#pragma unroll
      for (int r = 0; r < 4; ++r) {
        int m = rbase + r;
        float v = (acc[mi][ni][r] + bcol) * scale;
        bf16_t h = (bf16_t)v;
        if (z == 0) {
          qb[(size_t)m * CC + col] = h;
        } else if (z == 1) {
          kb[(size_t)m * CC + col] = h;
        } else {
          int b = m >> 11, tt = m & (TT - 1);
          vt[((size_t)b * CC + col) * TT + tt] = h;  // v^T: [B][H][T]
        }
      }
    }
  }
}

// ---------------------------------------------------------------------------
// Kernel 4: S = q k^T (scale folded into q), causal mask + (==0 -> -inf),
// stored fp16.  Only lower-triangular 128x128 blocks computed.
// ---------------------------------------------------------------------------
__global__ __launch_bounds__(256) void s_gemm_kernel(
    const bf16_t* __restrict__ qb, const bf16_t* __restrict__ kb,
    _Float16* __restrict__ S) {
  int tj = blockIdx.x, ti = blockIdx.y, b = blockIdx.z;
  if (tj > ti) return;
  __shared__ bf16_t As0[4096], As1[4096], Bs0[4096], Bs1[4096];
  int m0 = ti * 128, n0 = tj * 128;

  f32x4 acc[4][4];
#pragma unroll
  for (int i = 0; i < 4; ++i)
#pragma unroll
    for (int j = 0; j < 4; ++j) acc[i][j] = (f32x4){0.f, 0.f, 0.f, 0.f};

  const bf16_t* A = qb + ((size_t)b * TT + m0) * CC;
  const bf16_t* B = kb + ((size_t)b * TT + n0) * CC;
  gemm_core(A, CC, B, CC, CC / 32, As0, As1, Bs0, Bs1, acc);

  _Float16* Sb = S + (size_t)b * TT * TT;
  int l = threadIdx.x & 63, w = threadIdx.x >> 6;
  int wr = (w >> 1) * 64, wc = (w & 1) * 64;
#pragma unroll
  for (int mi = 0; mi < 4; ++mi) {
#pragma unroll
    for (int ni = 0; ni < 4; ++ni) {
      int j = n0 + wc + ni * 16 + (l & 15);
      int ibase = m0 + wr + mi * 16 + (l >> 4) * 4;
#pragma unroll
      for (int r = 0; r < 4; ++r) {
        int i = ibase + r;
        float v = acc[mi][ni][r];
        if (j > i || v == 0.0f) v = -INFINITY;  // causal + reference quirk
        Sb[(size_t)i * TT + j] = (_Float16)v;
      }
    }
  }
}

// ---------------------------------------------------------------------------
// Kernel 5: rowstat+normalize — per-row max M, L = sum exp(s-M); writes
// P = exp(s-M)/L as bf16, rows zero-padded to the next 128 boundary.
// One half8 load / bf16x8 store per thread (pe <= 2048 = 256*8).
// ---------------------------------------------------------------------------
__global__ __launch_bounds__(256) void rowstat_kernel(
    const _Float16* __restrict__ S, bf16_t* __restrict__ P) {
  int row = blockIdx.x & (TT - 1);
  int b = blockIdx.x >> 11;
  const _Float16* s = S + ((size_t)b * TT + row) * TT;
  bf16_t* p = P + ((size_t)b * TT + row) * TT;
  int pe = ((row >> 7) + 1) << 7;  // padded causal length, multiple of 128
  int j = threadIdx.x * 8;
  bool live = j < pe;

  float f[8];
  if (live) {
    half8 h = *(const half8*)(s + j);
#pragma unroll
    for (int k = 0; k < 8; ++k) f[k] = (float)h[k];
  } else {
#pragma unroll
    for (int k = 0; k < 8; ++k) f[k] = -INFINITY;
  }

  float m = f[0];
#pragma unroll
  for (int k = 1; k < 8; ++k) m = fmaxf(m, f[k]);
#pragma unroll
  for (int off = 32; off > 0; off >>= 1) m = fmaxf(m, __shfl_xor(m, off));
  __shared__ float redm[4];
  int w = threadIdx.x >> 6, l = threadIdx.x & 63;
  if (l == 0) redm[w] = m;
  __syncthreads();
  m = fmaxf(fmaxf(redm[0], redm[1]), fmaxf(redm[2], redm[3]));

  float e[8];
  float sum = 0.f;
#pragma unroll
  for (int k = 0; k < 8; ++k) {
    e[k] = __expf(f[k] - m);  // exp(-inf)=0 for masked slots
    sum += e[k];
  }
#pragma unroll
  for (int off = 32; off > 0; off >>= 1) sum += __shfl_xor(sum, off);
  __shared__ float reds[4];
  if (l == 0) reds[w] = sum;
  __syncthreads();
  float inv = 1.0f / (reds[0] + reds[1] + reds[2] + reds[3]);

  if (live) {
    bf16x8 o;
#pragma unroll
    for (int k = 0; k < 8; ++k) o[k] = (bf16_t)(e[k] * inv);
    *(bf16x8*)(p + j) = o;
  }
}

// ---------------------------------------------------------------------------
// Kernel 6: O = P @ V   (A = P row-major [T][T], Bt = v^T [B][H][T]).
// Fully async staging, no exp.  K-loop truncated at the causal boundary.
// Heaviest m-tiles dispatched first (ti reversed).
// ---------------------------------------------------------------------------
__global__ __launch_bounds__(256) void o_gemm_kernel(
    const bf16_t* __restrict__ P, const bf16_t* __restrict__ vt,
    float* __restrict__ out) {
  int nj = blockIdx.x;
  int ti = (int)gridDim.y - 1 - (int)blockIdx.y;  // heavy first
  int b = blockIdx.z;
  __shared__ bf16_t As0[4096], As1[4096], Bs0[4096], Bs1[4096];
  int m0 = ti * 128, n0 = nj * 128;

  f32x4 acc[4][4];
#pragma unroll
  for (int i = 0; i < 4; ++i)
#pragma unroll
    for (int j = 0; j < 4; ++j) acc[i][j] = (f32x4){0.f, 0.f, 0.f, 0.f};

  const bf16_t* A = P + ((size_t)b * TT + m0) * TT;
  const bf16_t* B = vt + ((size_t)b * CC + n0) * TT;
  gemm_core(A, TT, B, TT, (ti + 1) * 4, As0, As1, Bs0, Bs1, acc);

  float* Ob = out + (size_t)b * TT * CC;
  int l = threadIdx.x & 63, w = threadIdx.x >> 6;
  int wr = (w >> 1) * 64, wc = (w & 1) * 64;
#pragma unroll
  for (int mi = 0; mi < 4; ++mi) {
#pragma unroll
    for (int ni = 0; ni < 4; ++ni) {
      int col = n0 + wc + ni * 16 + (l & 15);
      int ibase = m0 + wr + mi * 16 + (l >> 4) * 4;
#pragma unroll
      for (int r = 0; r < 4; ++r)
        Ob[(size_t)(ibase + r) * CC + col] = acc[mi][ni][r];
    }
  }
}

// ---------------------------------------------------------------------------
extern "C" void kernel_launch(void* const* d_in, const int* in_sizes, int n_in,
                              void* d_out, int out_size, void* d_ws,
                              size_t ws_size, hipStream_t stream) {
  const float* x = (const float*)d_in[0];
  const float* Wq = (const float*)d_in[1];
  const float* bq = (const float*)d_in[2];
  const float* Wk = (const float*)d_in[3];
  const float* bk = (const float*)d_in[4];
  const float* Wv = (const float*)d_in[5];
  const float* bv = (const float*)d_in[6];
  float* out = (float*)d_out;

  char* ws = (char*)d_ws;
  size_t off = 0;
  auto carve = [&](size_t bytes) -> char* {
    char* p = ws + off;
    off += (bytes + 255) & ~(size_t)255;
    return p;
  };
  const size_t M = (size_t)BB * TT;  // 8192
  bf16_t* xbf = (bf16_t*)carve(M * CC * 2);            // 12.6 MB
  bf16_t* wt  = (bf16_t*)carve(3ull * CC * CC * 2);    // 3.5 MB
  bf16_t* qb  = (bf16_t*)carve(M * CC * 2);            // 12.6 MB
  bf16_t* kb  = (bf16_t*)carve(M * CC * 2);            // 12.6 MB
  bf16_t* vt  = (bf16_t*)carve(M * CC * 2);            // 12.6 MB (as [B][H][T])
  _Float16* S = (_Float16*)carve((size_t)BB * TT * TT * 2);  // 33.5 MB
  bf16_t* P   = (bf16_t*)carve((size_t)BB * TT * TT * 2);    // 33.5 MB
  (void)off; (void)ws_size;

  // 1+2: input prep
  cast_x_kernel<<<(M * CC / 8 + 255) / 256, 256, 0, stream>>>(x, xbf);
  transpose_w_kernel<<<dim3(CC / 32, CC / 32, 3), dim3(32, 8, 1), 0, stream>>>(
      Wq, Wk, Wv, wt);
  // 3: q,k,v
  qkv_gemm_kernel<<<dim3(CC / 128, M / 128, 3), 256, 0, stream>>>(
      xbf, wt, bq, bk, bv, qb, kb, vt);
  // 4: S = q k^T (lower-tri blocks, fp16)
  s_gemm_kernel<<<dim3(TT / 128, TT / 128, BB), 256, 0, stream>>>(qb, kb, S);
  // 5: softmax rows -> P (bf16, zero-padded)
  rowstat_kernel<<<BB * TT, 256, 0, stream>>>(S, P);
  // 6: O = P V
  o_gemm_kernel<<<dim3(CC / 128, TT / 128, BB), 256, 0, stream>>>(P, vt, out);
}